// Round 11
// baseline (196.696 us; speedup 1.0000x reference)
//
#include <hip/hip_runtime.h>

#define NBLK 256
#define FPAD 16   // 64 B per flag slot

typedef float v2f __attribute__((ext_vector_type(2)));

#define AG_LD(p)    __hip_atomic_load((p), __ATOMIC_RELAXED, __HIP_MEMORY_SCOPE_AGENT)
#define AG_ST(p, v) __hip_atomic_store((p), (v), __ATOMIC_RELAXED, __HIP_MEMORY_SCOPE_AGENT)

// Global fan-out barrier (validated R5-R10) — used ONCE, after P0, with the
// acquire fence that publishes the transposed weights and kills stale poison.
__device__ __forceinline__ void gridbar(int n, unsigned* flags, unsigned* rel,
                                        int bid) {
    __syncthreads();
    if (threadIdx.x == 0)
        __hip_atomic_store(&flags[bid * FPAD], (unsigned)n, __ATOMIC_RELEASE,
                           __HIP_MEMORY_SCOPE_AGENT);
    if (bid == 0) {
        if (threadIdx.x < NBLK) {
            while ((int)__hip_atomic_load(&flags[threadIdx.x * FPAD],
                                          __ATOMIC_RELAXED,
                                          __HIP_MEMORY_SCOPE_AGENT) < n)
                __builtin_amdgcn_s_sleep(1);
        }
        __syncthreads();
        if (threadIdx.x < 16)
            __hip_atomic_store(&rel[(n * 16 + threadIdx.x) * FPAD], (unsigned)n,
                               __ATOMIC_RELEASE, __HIP_MEMORY_SCOPE_AGENT);
    } else {
        if (threadIdx.x == 0) {
            while ((int)__hip_atomic_load(&rel[(n * 16 + (bid & 15)) * FPAD],
                                          __ATOMIC_RELAXED,
                                          __HIP_MEMORY_SCOPE_AGENT) < n)
                __builtin_amdgcn_s_sleep(1);
        }
    }
    __builtin_amdgcn_fence(__ATOMIC_ACQUIRE, "agent");
    __syncthreads();
}

// Per-batch sync: poll the 16 stamped flag lines of batch b until >= need.
// Stamps are monotone (i+2), poison (0xAA..) is negative -> always unarmed.
__device__ __forceinline__ void batch_sync(int need, const unsigned* pflags,
                                           int b) {
    if (threadIdx.x < 16) {
        const unsigned* pf = pflags + (size_t)(b * 16 + (int)threadIdx.x) * FPAD;
        while ((int)AG_LD(pf) < need) __builtin_amdgcn_s_sleep(1);
    }
    __syncthreads();
}

// Per-batch softmax combine + sigmoid + U2 matvec + updB (validated R9).
// 512 threads: c=tid&255, rq=tid>>8.
__device__ __forceinline__ float phaseB(int i, int b, int c, int rq,
                                        const float* __restrict__ part,
                                        const float* __restrict__ WtB,
                                        const float* __restrict__ updB,
                                        float* sc, float* aggl) {
    float M = -1e30f, den = 0.f, num = 0.f;
    const int par = i & 1;
    #pragma unroll
    for (int j = rq * 8; j < rq * 8 + 8; ++j) {
        const float* pp = part + (size_t)(par * 256 + b * 16 + j) * 768;
        const float mj = AG_LD(pp + c);
        const float dj = AG_LD(pp + 256 + c);
        const float nj = AG_LD(pp + 512 + c);
        const float Mn = fmaxf(M, mj);
        const float s = __expf(M - Mn), e = __expf(mj - Mn);
        den = den * s + dj * e;
        num = num * s + nj * e;
        M = Mn;
    }
    sc[rq * 256 + c] = M;
    sc[512 + rq * 256 + c] = den;
    sc[1024 + rq * 256 + c] = num;
    __syncthreads();
    if (rq == 0) {
        const float m0 = sc[c], m1 = sc[256 + c];
        const float Mx = fmaxf(m0, m1);
        const float s0 = __expf(m0 - Mx), s1 = __expf(m1 - Mx);
        const float dd = sc[512 + c] * s0 + sc[768 + c] * s1;
        const float nn = sc[1024 + c] * s0 + sc[1280 + c] * s1;
        aggl[c] = 1.f / (1.f + __expf(-(nn / dd)));
    }
    __syncthreads();
    const float4* U2q = (const float4*)(WtB + (size_t)(9 + i) * 65536);
    const int kg0 = rq * 32;
    float4 buf[8];
    #pragma unroll
    for (int j = 0; j < 8; ++j) buf[j] = U2q[(size_t)(kg0 + j) * 256 + c];
    v2f au = {0.f, 0.f};
    #pragma unroll
    for (int ph = 0; ph < 4; ++ph) {
        #pragma unroll
        for (int j = 0; j < 8; ++j) {
            const float4 w4 = buf[j];
            if (ph < 3) buf[j] = U2q[(size_t)(kg0 + (ph + 1) * 8 + j) * 256 + c];
            const float4 ag = *(const float4*)&aggl[(kg0 + ph * 8 + j) * 4];
            au += (v2f){ag.x, ag.y} * (v2f){w4.x, w4.y};
            au += (v2f){ag.z, ag.w} * (v2f){w4.z, w4.w};
        }
    }
    __syncthreads();
    sc[rq * 256 + c] = au.x + au.y;
    __syncthreads();
    return sc[c] + sc[256 + c] + updB[i * 256 + c];
}

// Persistent kernel, R9 compute structure + per-batch sync + feat pre-stage.
__global__ __launch_bounds__(512, 2) void fused_k(
    const float* __restrict__ feat,   // [16][128][256]
    const float* __restrict__ mask,   // [16][128]
    const float* __restrict__ aggW,   // [3][256][256]
    const float* __restrict__ aggB,   // [3][256]
    const float* __restrict__ attnW,  // [3][256][512]
    const float* __restrict__ updW,   // [3][256][512]
    const float* __restrict__ updB,   // [3][256]
    float* __restrict__ WtB,          // 12 * 65536 packed k-quad layout
    float* __restrict__ part,         // 2 * 256 * 768
    unsigned* flags, unsigned* rel, unsigned* pflags,
    float* __restrict__ out)
{
    __shared__ float ldsa[6408];  // hidl[0,2048) xl[2048,4096) sc[4096,6144)
                                  // aggl[6144,6400) msk[6400,6408)
    float* hidl = ldsa;           // survives the P0 fence (feat*mask staged)
    float* xl   = ldsa + 2048;
    float* sc   = ldsa + 4096;    // 2048 floats (P1 reduce uses 8*256)
    float* aggl = ldsa + 6144;
    float* msk  = ldsa + 6400;

    const int bid = blockIdx.x;
    const int tid = threadIdx.x;
    const int c  = tid & 255;
    const int rq = tid >> 8;                  // 0..1, wave-uniform
    const int b  = bid >> 4, jj = bid & 15;
    const int row0 = b * 128 + jj * 8;

    // ---- P0a: stage hid0 = feat*mask and the 8 mask values into LDS
    // (before the fence: LDS is not invalidated, so no post-fence refetch)
    #pragma unroll
    for (int r = 0; r < 4; ++r) {
        const int rl = rq * 4 + r;
        hidl[rl * 256 + c] = feat[(size_t)(row0 + rl) * 256 + c] * mask[row0 + rl];
    }
    if (tid < 8) msk[tid] = mask[row0 + tid];

    // ---- P0b: transpose+pack 12 weight mats (blocks 0..191); Tl at +2048
    if (bid < 192) {
        float (*Tl)[65] = (float (*)[65])(ldsa + 2048);
        const int m = bid >> 4, t = bid & 15, tr = t >> 2, tc = t & 3;
        const float* src; int stride, off;
        if (m < 3)      { src = aggW  + (size_t)m * 65536;        stride = 256; off = 0;   }
        else if (m < 6) { src = attnW + (size_t)(m - 3) * 131072; stride = 512; off = 0;   }
        else if (m < 9) { src = updW  + (size_t)(m - 6) * 131072; stride = 512; off = 0;   }
        else            { src = updW  + (size_t)(m - 9) * 131072; stride = 512; off = 256; }
        float* dst = WtB + (size_t)m * 65536;
        #pragma unroll
        for (int it = 0; it < 2; ++it) {
            const int j = it * 512 + tid, row = j >> 4, q = (j & 15) * 4;
            const float4 v = *(const float4*)(src + (size_t)(tr * 64 + row) * stride + off + tc * 64 + q);
            Tl[row][q + 0] = v.x; Tl[row][q + 1] = v.y;
            Tl[row][q + 2] = v.z; Tl[row][q + 3] = v.w;
        }
        __syncthreads();
        #pragma unroll
        for (int it = 0; it < 2; ++it) {
            const int j = it * 512 + tid, kgl = j >> 6, cl = j & 63;
            float4 v;
            v.x = Tl[cl][kgl * 4 + 0]; v.y = Tl[cl][kgl * 4 + 1];
            v.z = Tl[cl][kgl * 4 + 2]; v.w = Tl[cl][kgl * 4 + 3];
            *(float4*)(dst + (size_t)(tc * 16 + kgl) * 1024 + (tr * 64 + cl) * 4) = v;
        }
    }
    gridbar(1, flags, rel, bid);   // ONLY global barrier (fence: publish WtB)

    float xu[8];                   // rq1: xU1 rows (persist across steps)
    #pragma unroll
    for (int r = 0; r < 8; ++r) xu[r] = 0.f;
    float accU = 0.f;

    for (int i = 0; i < 3; ++i) {
        if (i > 0) {
            batch_sync(i + 1, pflags, b);            // step i-1 partials ready
            accU = phaseB(i - 1, b, c, rq, part, WtB, updB, sc, aggl);
            if (rq == 1) {
                #pragma unroll
                for (int r = 0; r < 8; ++r)
                    hidl[r * 256 + c] = (xu[r] + accU) * msk[r];
            }
            __syncthreads();
        }
        // (i == 0: hidl pre-staged in P0a)

        // ---- P1: x = hid @ aggW^T + aggB. rq halves SPLIT K, depth-8
        // packed prefetch, v2f over k-pairs, 8 rows/thread. (validated R9)
        {
            const float4* Wq = (const float4*)(WtB + (size_t)i * 65536);
            const int kg0 = rq * 32;
            float4 buf[8];
            #pragma unroll
            for (int j = 0; j < 8; ++j) buf[j] = Wq[(size_t)(kg0 + j) * 256 + c];
            v2f acc[8];
            #pragma unroll
            for (int r = 0; r < 8; ++r) acc[r] = (v2f){0.f, 0.f};
            #pragma unroll
            for (int ph = 0; ph < 4; ++ph) {
                #pragma unroll
                for (int j = 0; j < 8; ++j) {
                    const float4 w = buf[j];
                    if (ph < 3) buf[j] = Wq[(size_t)(kg0 + (ph + 1) * 8 + j) * 256 + c];
                    const int kq = (kg0 + ph * 8 + j) * 4;
                    #pragma unroll
                    for (int r = 0; r < 8; ++r) {
                        const float4 h = *(const float4*)&hidl[r * 256 + kq];
                        acc[r] += (v2f){h.x, h.y} * (v2f){w.x, w.y};
                        acc[r] += (v2f){h.z, h.w} * (v2f){w.z, w.w};
                    }
                }
            }
            if (rq == 1) {
                #pragma unroll
                for (int r = 0; r < 8; ++r) sc[r * 256 + c] = acc[r].x + acc[r].y;
            }
            __syncthreads();
            if (rq == 0) {
                const float bb = aggB[i * 256 + c];
                #pragma unroll
                for (int r = 0; r < 8; ++r)
                    xl[r * 256 + c] = acc[r].x + acc[r].y + sc[r * 256 + c] + bb;
            }
            __syncthreads();
        }

        // ---- P2: rq0 streams W1 -> p ; rq1 streams U1 -> xU1 (validated R9)
        float pr[8];
        {
            const float4* Sq = (const float4*)(WtB + (size_t)((rq ? 6 : 3) + i) * 65536);
            float4 buf[8];
            #pragma unroll
            for (int j = 0; j < 8; ++j) buf[j] = Sq[(size_t)j * 256 + c];
            v2f acc[8];
            #pragma unroll
            for (int r = 0; r < 8; ++r) acc[r] = (v2f){0.f, 0.f};
            #pragma unroll
            for (int ph = 0; ph < 8; ++ph) {
                #pragma unroll
                for (int j = 0; j < 8; ++j) {
                    const float4 w = buf[j];
                    if (ph < 7) buf[j] = Sq[(size_t)((ph + 1) * 8 + j) * 256 + c];
                    const int kq = (ph * 8 + j) * 4;
                    #pragma unroll
                    for (int r = 0; r < 8; ++r) {
                        const float4 xk = *(const float4*)&xl[r * 256 + kq];
                        acc[r] += (v2f){xk.x, xk.y} * (v2f){w.x, w.y};
                        acc[r] += (v2f){xk.z, xk.w} * (v2f){w.z, w.w};
                    }
                }
            }
            #pragma unroll
            for (int r = 0; r < 8; ++r) pr[r] = acc[r].x + acc[r].y;
        }
        if (rq == 1) {
            #pragma unroll
            for (int r = 0; r < 8; ++r) xu[r] = pr[r];
        } else {
            // ---- online-softmax partial over this block's 8 rows
            float m8 = pr[0];
            #pragma unroll
            for (int r = 1; r < 8; ++r) m8 = fmaxf(m8, pr[r]);
            float d8 = 0.f, n8 = 0.f;
            #pragma unroll
            for (int r = 0; r < 8; ++r) {
                const float e = __expf(pr[r] - m8);
                d8 += e;
                n8 += e * xl[r * 256 + c];
            }
            float* pb = part + (size_t)((i & 1) * 256 + bid) * 768;
            AG_ST(pb + c, m8);
            AG_ST(pb + 256 + c, d8);
            AG_ST(pb + 512 + c, n8);
        }
        // publish stamp i+2 (syncthreads drains the AG_STs: vmcnt(0) precedes
        // s_barrier), then one release store to this block's own flag line.
        __syncthreads();
        if (tid == 0)
            __hip_atomic_store(&pflags[(size_t)bid * FPAD], (unsigned)(i + 2),
                               __ATOMIC_RELEASE, __HIP_MEMORY_SCOPE_AGENT);
    }

    // ---- final combine + epilogue: out = xU1 + accU (rq1 holds xU1)
    batch_sync(4, pflags, b);
    accU = phaseB(2, b, c, rq, part, WtB, updB, sc, aggl);
    if (rq == 1) {
        #pragma unroll
        for (int r = 0; r < 8; ++r)
            out[(size_t)(row0 + r) * 256 + c] = xu[r] + accU;
    }
}

extern "C" void kernel_launch(void* const* d_in, const int* in_sizes, int n_in,
                              void* d_out, int out_size, void* d_ws, size_t ws_size,
                              hipStream_t stream) {
    const float* feat  = (const float*)d_in[0];
    const float* mask  = (const float*)d_in[1];
    const float* aggW  = (const float*)d_in[2];
    const float* aggB  = (const float*)d_in[3];
    const float* attnW = (const float*)d_in[4];
    // d_in[5] = attnB: cancels in softmax (constant along the s axis)
    const float* updW  = (const float*)d_in[6];
    const float* updB  = (const float*)d_in[7];

    float* WtB  = (float*)d_ws;                        // 12 * 65536 floats
    float* part = WtB + 12 * 65536;                    // 2 * 256 * 768 floats
    unsigned* flags  = (unsigned*)(part + 2 * 256 * 768);
    unsigned* rel    = flags + NBLK * FPAD;            // 10 barriers * 16 lines
    unsigned* pflags = rel + 160 * FPAD;               // 256 stamped lines

    fused_k<<<NBLK, 512, 0, stream>>>(
        feat, mask, aggW, aggB, attnW, updW, updB,
        WtB, part, flags, rel, pflags, (float*)d_out);
}

// Round 12
// 149.449 us; speedup vs baseline: 1.3161x; 1.3161x over previous
//
#include <hip/hip_runtime.h>
#include <hip/hip_fp16.h>

#define NBLK 256
#define FPAD 16   // 64 B per flag slot

typedef _Float16 h2_t __attribute__((ext_vector_type(2)));

#define AG_LD(p)    __hip_atomic_load((p), __ATOMIC_RELAXED, __HIP_MEMORY_SCOPE_AGENT)
#define AG_ST(p, v) __hip_atomic_store((p), (v), __ATOMIC_RELAXED, __HIP_MEMORY_SCOPE_AGENT)

// pack two fp32 -> fp16 pair (RNE)
__device__ __forceinline__ unsigned pkh(float a, float b) {
    const __half2 h = __floats2half2_rn(a, b);
    return __builtin_bit_cast(unsigned, h);
}
// fp16-pair dot product with fp32 accumulate (v_dot2_f32_f16)
__device__ __forceinline__ float fdot2(unsigned w, unsigned a, float c) {
#if __has_builtin(__builtin_amdgcn_fdot2)
    return __builtin_amdgcn_fdot2(__builtin_bit_cast(h2_t, w),
                                  __builtin_bit_cast(h2_t, a), c, false);
#else
    const float2 fw = __half22float2(__builtin_bit_cast(__half2, w));
    const float2 fa = __half22float2(__builtin_bit_cast(__half2, a));
    return c + fw.x * fa.x + fw.y * fa.y;
#endif
}

// Global fan-out barrier (validated R5-R10; R11's per-batch variant regressed).
// fence=true only after P0 (publish packed weights, kill stale poison).
__device__ __forceinline__ void gridbar(int n, unsigned* flags, unsigned* rel,
                                        int bid, bool fence) {
    __syncthreads();
    if (threadIdx.x == 0)
        __hip_atomic_store(&flags[bid * FPAD], (unsigned)n, __ATOMIC_RELEASE,
                           __HIP_MEMORY_SCOPE_AGENT);
    if (bid == 0) {
        if (threadIdx.x < NBLK) {
            while ((int)__hip_atomic_load(&flags[threadIdx.x * FPAD],
                                          __ATOMIC_RELAXED,
                                          __HIP_MEMORY_SCOPE_AGENT) < n)
                __builtin_amdgcn_s_sleep(1);
        }
        __syncthreads();
        if (threadIdx.x < 16)
            __hip_atomic_store(&rel[(n * 16 + threadIdx.x) * FPAD], (unsigned)n,
                               __ATOMIC_RELEASE, __HIP_MEMORY_SCOPE_AGENT);
    } else {
        if (threadIdx.x == 0) {
            while ((int)__hip_atomic_load(&rel[(n * 16 + (bid & 15)) * FPAD],
                                          __ATOMIC_RELAXED,
                                          __HIP_MEMORY_SCOPE_AGENT) < n)
                __builtin_amdgcn_s_sleep(1);
        }
    }
    if (fence) __builtin_amdgcn_fence(__ATOMIC_ACQUIRE, "agent");
    __syncthreads();
}

// Packed fp16 weight layout: octet g = k>>3; uint at WtH[m*32768 + g*1024 +
// c*4 + ((k>>1)&3)] holds k-pair (2k, 2k+1). Lane c loads uint4 = 8 k-values.

// Per-batch softmax combine + sigmoid + U2 matvec (fp16, k-split) + updB.
__device__ __forceinline__ float phaseB(int i, int b, int c, int rq, int tid,
                                        const float* __restrict__ part,
                                        const unsigned* __restrict__ WtH,
                                        const float* __restrict__ updB,
                                        float* sc, float* aggl32,
                                        unsigned* aggh) {
    float M = -1e30f, den = 0.f, num = 0.f;
    const int par = i & 1;
    #pragma unroll
    for (int j = rq * 8; j < rq * 8 + 8; ++j) {
        const float* pp = part + (size_t)(par * 256 + b * 16 + j) * 768;
        const float mj = AG_LD(pp + c);
        const float dj = AG_LD(pp + 256 + c);
        const float nj = AG_LD(pp + 512 + c);
        const float Mn = fmaxf(M, mj);
        const float s = __expf(M - Mn), e = __expf(mj - Mn);
        den = den * s + dj * e;
        num = num * s + nj * e;
        M = Mn;
    }
    sc[rq * 256 + c] = M;
    sc[512 + rq * 256 + c] = den;
    sc[1024 + rq * 256 + c] = num;
    __syncthreads();
    if (rq == 0) {
        const float m0 = sc[c], m1 = sc[256 + c];
        const float Mx = fmaxf(m0, m1);
        const float s0 = __expf(m0 - Mx), s1 = __expf(m1 - Mx);
        const float dd = sc[512 + c] * s0 + sc[768 + c] * s1;
        const float nn = sc[1024 + c] * s0 + sc[1280 + c] * s1;
        aggl32[c] = 1.f / (1.f + __expf(-(nn / dd)));
    }
    __syncthreads();
    if (tid < 128) aggh[tid] = pkh(aggl32[2 * tid], aggl32[2 * tid + 1]);
    __syncthreads();
    const unsigned* Uq = WtH + (size_t)(9 + i) * 32768;
    const int g0 = rq * 16;
    uint4 buf[8];
    #pragma unroll
    for (int j = 0; j < 8; ++j)
        buf[j] = *(const uint4*)(Uq + (size_t)(g0 + j) * 1024 + c * 4);
    float au = 0.f;
    #pragma unroll
    for (int ph = 0; ph < 2; ++ph) {
        #pragma unroll
        for (int j = 0; j < 8; ++j) {
            const uint4 w = buf[j];
            if (ph < 1)
                buf[j] = *(const uint4*)(Uq + (size_t)(g0 + 8 + j) * 1024 + c * 4);
            const uint4 a = *(const uint4*)&aggh[(g0 + ph * 8 + j) * 4];
            au = fdot2(w.x, a.x, au);
            au = fdot2(w.y, a.y, au);
            au = fdot2(w.z, a.z, au);
            au = fdot2(w.w, a.w, au);
        }
    }
    __syncthreads();
    sc[rq * 256 + c] = au;
    __syncthreads();
    return sc[c] + sc[256 + c] + updB[i * 256 + c];
}

__global__ __launch_bounds__(512, 2) void fused_k(
    const float* __restrict__ feat,   // [16][128][256]
    const float* __restrict__ mask,   // [16][128]
    const float* __restrict__ aggW,   // [3][256][256]
    const float* __restrict__ aggB,   // [3][256]
    const float* __restrict__ attnW,  // [3][256][512]
    const float* __restrict__ updW,   // [3][256][512]
    const float* __restrict__ updB,   // [3][256]
    unsigned* __restrict__ WtH,       // 12 * 32768 uints (fp16-pair packed)
    float* __restrict__ part,         // 2 * 256 * 768
    unsigned* flags, unsigned* rel,
    float* __restrict__ out)
{
    __shared__ __align__(16) float ldsf[6536];
    unsigned* hidh   = (unsigned*)ldsf;          // [0,1024)   8 rows x 128 pairs
    unsigned* xlh    = (unsigned*)ldsf + 1024;   // [1024,2048)
    float*    xl32   = ldsf + 2048;              // [2048,4096) 8 x 256 fp32
    float*    sc     = ldsf + 4096;              // [4096,6144)
    float*    aggl32 = ldsf + 6144;              // [6144,6400)
    unsigned* aggh   = (unsigned*)ldsf + 6400;   // [6400,6528)
    float*    msk    = ldsf + 6528;              // [6528,6536)

    const int bid = blockIdx.x;
    const int tid = threadIdx.x;
    const int c  = tid & 255;
    const int rq = tid >> 8;                  // 0..1, wave-uniform
    const int b  = bid >> 4, jj = bid & 15;
    const int row0 = b * 128 + jj * 8;

    // ---- P0a: stage hid0 = fp16(feat*mask) + mask into LDS (survives fence)
    #pragma unroll
    for (int it = 0; it < 2; ++it) {
        const int j = it * 512 + tid, r = j >> 7, pr = j & 127;
        const float2 f = *(const float2*)(feat + (size_t)(row0 + r) * 256 + pr * 2);
        const float mv = mask[row0 + r];
        hidh[r * 128 + pr] = pkh(f.x * mv, f.y * mv);
    }
    if (tid < 8) msk[tid] = mask[row0 + tid];

    // ---- P0b: transpose + fp16-pack 12 weight mats (blocks 0..191)
    if (bid < 192) {
        float (*Tl)[65] = (float (*)[65])(ldsf + 2048);   // overlay, dead regions
        const int m = bid >> 4, t = bid & 15, tr = t >> 2, tc = t & 3;
        const float* src; int stride, off;
        if (m < 3)      { src = aggW  + (size_t)m * 65536;        stride = 256; off = 0;   }
        else if (m < 6) { src = attnW + (size_t)(m - 3) * 131072; stride = 512; off = 0;   }
        else if (m < 9) { src = updW  + (size_t)(m - 6) * 131072; stride = 512; off = 0;   }
        else            { src = updW  + (size_t)(m - 9) * 131072; stride = 512; off = 256; }
        unsigned* dstu = WtH + (size_t)m * 32768;
        #pragma unroll
        for (int it = 0; it < 2; ++it) {
            const int j = it * 512 + tid, row = j >> 4, q = (j & 15) * 4;
            const float4 v = *(const float4*)(src + (size_t)(tr * 64 + row) * stride + off + tc * 64 + q);
            Tl[row][q + 0] = v.x; Tl[row][q + 1] = v.y;
            Tl[row][q + 2] = v.z; Tl[row][q + 3] = v.w;
        }
        __syncthreads();
        #pragma unroll
        for (int it = 0; it < 4; ++it) {
            const int j = it * 512 + tid, cl = j >> 5, pr = j & 31;
            const unsigned val = pkh(Tl[cl][pr * 2], Tl[cl][pr * 2 + 1]);
            const int P = tc * 32 + pr, g = P >> 2, jq = P & 3;
            dstu[(size_t)g * 1024 + (tr * 64 + cl) * 4 + jq] = val;
        }
    }
    gridbar(1, flags, rel, bid, true);   // only fenced barrier

    float xu[8];
    #pragma unroll
    for (int r = 0; r < 8; ++r) xu[r] = 0.f;
    float accU = 0.f;

    for (int i = 0; i < 3; ++i) {
        if (i > 0) {
            accU = phaseB(i - 1, b, c, rq, tid, part, WtH, updB, sc, aggl32, aggh);
            __syncthreads();            // protect sc reuse below
            if (rq == 1) {
                #pragma unroll
                for (int r = 0; r < 8; ++r)
                    sc[r * 256 + c] = (xu[r] + accU) * msk[r];
            }
            __syncthreads();
            #pragma unroll
            for (int it = 0; it < 2; ++it) {
                const int j = it * 512 + tid, r = j >> 7, pr = j & 127;
                hidh[r * 128 + pr] = pkh(sc[r * 256 + pr * 2], sc[r * 256 + pr * 2 + 1]);
            }
            __syncthreads();
        }

        // ---- P1: x = hid @ aggW^T + aggB. fp16 streams, rq halves split k.
        {
            const unsigned* Wq = WtH + (size_t)i * 32768;
            const int g0 = rq * 16;
            uint4 buf[8];
            #pragma unroll
            for (int j = 0; j < 8; ++j)
                buf[j] = *(const uint4*)(Wq + (size_t)(g0 + j) * 1024 + c * 4);
            float acc[8] = {};
            #pragma unroll
            for (int ph = 0; ph < 2; ++ph) {
                #pragma unroll
                for (int j = 0; j < 8; ++j) {
                    const uint4 w = buf[j];
                    if (ph < 1)
                        buf[j] = *(const uint4*)(Wq + (size_t)(g0 + 8 + j) * 1024 + c * 4);
                    const int g = g0 + ph * 8 + j;
                    #pragma unroll
                    for (int r = 0; r < 8; ++r) {
                        const uint4 h = *(const uint4*)&hidh[r * 128 + g * 4];
                        acc[r] = fdot2(w.x, h.x, acc[r]);
                        acc[r] = fdot2(w.y, h.y, acc[r]);
                        acc[r] = fdot2(w.z, h.z, acc[r]);
                        acc[r] = fdot2(w.w, h.w, acc[r]);
                    }
                }
            }
            if (rq == 1) {
                #pragma unroll
                for (int r = 0; r < 8; ++r) sc[r * 256 + c] = acc[r];
            }
            __syncthreads();
            if (rq == 0) {
                const float bb = aggB[i * 256 + c];
                #pragma unroll
                for (int r = 0; r < 8; ++r)
                    xl32[r * 256 + c] = acc[r] + sc[r * 256 + c] + bb;
            }
            __syncthreads();
            #pragma unroll
            for (int it = 0; it < 2; ++it) {
                const int j = it * 512 + tid, r = j >> 7, pr = j & 127;
                xlh[r * 128 + pr] = pkh(xl32[r * 256 + pr * 2], xl32[r * 256 + pr * 2 + 1]);
            }
            __syncthreads();
        }

        // ---- P2: rq0 streams W1 -> p ; rq1 streams U1 -> xU1 (fp16, full k)
        float pr8[8];
        {
            const unsigned* Sq = WtH + (size_t)((rq ? 6 : 3) + i) * 32768;
            uint4 buf[8];
            #pragma unroll
            for (int j = 0; j < 8; ++j)
                buf[j] = *(const uint4*)(Sq + (size_t)j * 1024 + c * 4);
            float acc[8] = {};
            #pragma unroll
            for (int ph = 0; ph < 4; ++ph) {
                #pragma unroll
                for (int j = 0; j < 8; ++j) {
                    const uint4 w = buf[j];
                    if (ph < 3)
                        buf[j] = *(const uint4*)(Sq + (size_t)((ph + 1) * 8 + j) * 1024 + c * 4);
                    const int g = ph * 8 + j;
                    #pragma unroll
                    for (int r = 0; r < 8; ++r) {
                        const uint4 h = *(const uint4*)&xlh[r * 128 + g * 4];
                        acc[r] = fdot2(w.x, h.x, acc[r]);
                        acc[r] = fdot2(w.y, h.y, acc[r]);
                        acc[r] = fdot2(w.z, h.z, acc[r]);
                        acc[r] = fdot2(w.w, h.w, acc[r]);
                    }
                }
            }
            #pragma unroll
            for (int r = 0; r < 8; ++r) pr8[r] = acc[r];
        }
        if (rq == 1) {
            #pragma unroll
            for (int r = 0; r < 8; ++r) xu[r] = pr8[r];
        } else {
            float m8 = pr8[0];
            #pragma unroll
            for (int r = 1; r < 8; ++r) m8 = fmaxf(m8, pr8[r]);
            float d8 = 0.f, n8 = 0.f;
            #pragma unroll
            for (int r = 0; r < 8; ++r) {
                const float e = __expf(pr8[r] - m8);
                d8 += e;
                n8 += e * xl32[r * 256 + c];
            }
            float* pb = part + (size_t)((i & 1) * 256 + bid) * 768;
            AG_ST(pb + c, m8);
            AG_ST(pb + 256 + c, d8);
            AG_ST(pb + 512 + c, n8);
        }
        gridbar(i + 2, flags, rel, bid, false);   // no fence: L2 stays warm
    }

    // ---- final combine + epilogue: out = xU1 + accU (fp32 path)
    accU = phaseB(2, b, c, rq, tid, part, WtH, updB, sc, aggl32, aggh);
    if (rq == 1) {
        #pragma unroll
        for (int r = 0; r < 8; ++r)
            out[(size_t)(row0 + r) * 256 + c] = xu[r] + accU;
    }
}

extern "C" void kernel_launch(void* const* d_in, const int* in_sizes, int n_in,
                              void* d_out, int out_size, void* d_ws, size_t ws_size,
                              hipStream_t stream) {
    const float* feat  = (const float*)d_in[0];
    const float* mask  = (const float*)d_in[1];
    const float* aggW  = (const float*)d_in[2];
    const float* aggB  = (const float*)d_in[3];
    const float* attnW = (const float*)d_in[4];
    // d_in[5] = attnB: cancels in softmax (constant along the s axis)
    const float* updW  = (const float*)d_in[6];
    const float* updB  = (const float*)d_in[7];

    unsigned* WtH = (unsigned*)d_ws;                   // 12 * 32768 uints
    float* part = (float*)(WtH + 12 * 32768);          // 2 * 256 * 768 floats
    unsigned* flags = (unsigned*)(part + 2 * 256 * 768);
    unsigned* rel   = flags + NBLK * FPAD;             // 10 barriers * 16 lines

    fused_k<<<NBLK, 512, 0, stream>>>(
        feat, mask, aggW, aggB, attnW, updW, updB,
        WtH, part, flags, rel, (float*)d_out);
}